// Round 2
// baseline (126.397 us; speedup 1.0000x reference)
//
#include <hip/hip_runtime.h>
#include <hip/hip_bf16.h>

// GAT layer, N=4096, HEADS=8, IN_F=256, OUT_F=64.
// Key identity: e[h,i,j] = e_src[h,i] + e_dst[h,j]; softmax over j kills the
// e_src term, so attention is row-independent and h_out[h,i,:] == row_h[:]
// for every i. Also e_dst = h @ (W[h] @ a2[h]) and row_h = (att^T h) @ W[h]
// -- full hp never materialized. adj is unused by the reference.
//
// Output layout: reference does h_out(H,N,O).reshape(N, H*O) -- a C-order
// flatten, NOT a transpose. Flat f = h*N*O + i*O + o, so out[f] = row_h[o]
// with h = f / (N*O), o = f % O.

#define HEADS 8
#define IN_F 256
#define OUT_F 64
#define NN 4096
#define ECHUNKS 16               // k_edst: 256 rows/block
#define GCHUNKS 32               // k_gpart: 128 rows/block
#define GROWS (NN / GCHUNKS)     // 128

// ---------------------------------------------------------------------------
// K1: e_dst[h,n] = h[n,:] . v[h,:],  v[h,k] = sum_o W[h,k,o]*a2[h,o]
// ---------------------------------------------------------------------------
__global__ void k_edst(const float* __restrict__ hmat,
                       const float* __restrict__ W,
                       const float* __restrict__ a,
                       float* __restrict__ e_dst) {
    const int blk   = blockIdx.x;
    const int head  = blk >> 4;          // /ECHUNKS
    const int chunk = blk & (ECHUNKS - 1);
    const int tid   = threadIdx.x;

    __shared__ float a2[OUT_F];
    __shared__ float v[IN_F];

    if (tid < OUT_F) a2[tid] = a[head * 2 * OUT_F + OUT_F + tid];
    __syncthreads();

    // v[k], one k per thread
    {
        const float4* Wr = reinterpret_cast<const float4*>(
            W + (size_t)(head * IN_F + tid) * OUT_F);
        float acc = 0.f;
#pragma unroll
        for (int o4 = 0; o4 < OUT_F / 4; ++o4) {
            float4 w4 = Wr[o4];
            acc += w4.x * a2[o4 * 4 + 0] + w4.y * a2[o4 * 4 + 1] +
                   w4.z * a2[o4 * 4 + 2] + w4.w * a2[o4 * 4 + 3];
        }
        v[tid] = acc;
    }
    __syncthreads();

    const int n = chunk * 256 + tid;
    const float4* hr = reinterpret_cast<const float4*>(hmat + (size_t)n * IN_F);
    float acc = 0.f;
#pragma unroll 8
    for (int k4 = 0; k4 < IN_F / 4; ++k4) {
        float4 h4 = hr[k4];
        acc += h4.x * v[k4 * 4 + 0] + h4.y * v[k4 * 4 + 1] +
               h4.z * v[k4 * 4 + 2] + h4.w * v[k4 * 4 + 3];
    }
    e_dst[head * NN + n] = acc;
}

// ---------------------------------------------------------------------------
// K2: per (head, chunk of 128 rows): recompute softmax stats over the full
// e_dst row (16 KB, L2-hot), then partial g[k] = sum_j att_j * h[j,k].
// ---------------------------------------------------------------------------
__global__ void k_gpart(const float* __restrict__ hmat,
                        const float* __restrict__ e_dst,
                        float* __restrict__ g_part) {
    const int blk   = blockIdx.x;
    const int head  = blk >> 5;          // /GCHUNKS
    const int chunk = blk & (GCHUNKS - 1);
    const int tid   = threadIdx.x;

    __shared__ float red[256];
    __shared__ float wts[GROWS];

    const float* e = e_dst + head * NN;

    // block max over 4096
    float m = -INFINITY;
    for (int i = tid; i < NN; i += 256) m = fmaxf(m, e[i]);
    red[tid] = m;
    __syncthreads();
    for (int s = 128; s > 0; s >>= 1) {
        if (tid < s) red[tid] = fmaxf(red[tid], red[tid + s]);
        __syncthreads();
    }
    m = red[0];
    __syncthreads();

    // block sum of exp
    float ssum = 0.f;
    for (int i = tid; i < NN; i += 256) ssum += __expf(e[i] - m);
    red[tid] = ssum;
    __syncthreads();
    for (int s = 128; s > 0; s >>= 1) {
        if (tid < s) red[tid] += red[tid + s];
        __syncthreads();
    }
    const float inv = 1.f / red[0];

    if (tid < GROWS)
        wts[tid] = __expf(e[chunk * GROWS + tid] - m) * inv;
    __syncthreads();

    // partial weighted row-sum; k = tid, coalesced across lanes
    const float* hb = hmat + (size_t)chunk * GROWS * IN_F;
    float acc = 0.f;
#pragma unroll 4
    for (int j = 0; j < GROWS; ++j)
        acc += wts[j] * hb[(size_t)j * IN_F + tid];
    g_part[(size_t)(head * GCHUNKS + chunk) * IN_F + tid] = acc;
}

// ---------------------------------------------------------------------------
// K3: reduce g partials, row_h[o] = sum_k g[k] * W[h,k,o]
// ---------------------------------------------------------------------------
__global__ void k_outrow(const float* __restrict__ W,
                         const float* __restrict__ g_part,
                         float* __restrict__ out_row) {
    const int head = blockIdx.x;
    const int tid  = threadIdx.x;

    __shared__ float g[IN_F];
    __shared__ float part[256];

    float acc = 0.f;
    for (int c = 0; c < GCHUNKS; ++c)
        acc += g_part[(size_t)(head * GCHUNKS + c) * IN_F + tid];
    g[tid] = acc;
    __syncthreads();

    const int o = tid & 63, grp = tid >> 6;
    float p = 0.f;
#pragma unroll 4
    for (int kk = 0; kk < 64; ++kk) {
        int k = grp * 64 + kk;
        p += g[k] * W[(size_t)(head * IN_F + k) * OUT_F + o];
    }
    part[tid] = p;
    __syncthreads();
    if (tid < 64)
        out_row[head * OUT_F + tid] =
            part[tid] + part[tid + 64] + part[tid + 128] + part[tid + 192];
}

// ---------------------------------------------------------------------------
// K4: fill output. Flat float index p: out[p] = row[p/(NN*OUT_F)][p % OUT_F].
// Per float4 idx (p = 4*idx): head = idx >> 16, o4 = idx & 15.
// grid: 2048 blocks x 256 threads, one float4 per thread (524288 float4).
// ---------------------------------------------------------------------------
__global__ void k_bcast(const float* __restrict__ out_row,
                        float4* __restrict__ out) {
    __shared__ float4 r[HEADS * OUT_F / 4];   // 128 float4 = 512 floats
    const int tid = threadIdx.x;
    if (tid < HEADS * OUT_F / 4)
        r[tid] = reinterpret_cast<const float4*>(out_row)[tid];
    __syncthreads();
    const size_t idx = (size_t)blockIdx.x * 256 + tid;   // float4 index
    const int head = (int)(idx >> 16);                   // 65536 float4/head
    const int o4   = (int)(idx & 15);                    // 16 float4 per 64 cols
    out[idx] = r[head * 16 + o4];
}

extern "C" void kernel_launch(void* const* d_in, const int* in_sizes, int n_in,
                              void* d_out, int out_size, void* d_ws, size_t ws_size,
                              hipStream_t stream) {
    const float* hmat = (const float*)d_in[0];
    // d_in[1] = adj : UNUSED by the reference
    const float* W = (const float*)d_in[2];
    const float* a = (const float*)d_in[3];
    float* out = (float*)d_out;
    float* ws  = (float*)d_ws;

    float* e_dst   = ws;                               // 8*4096   = 32768 f
    float* g_part  = e_dst + HEADS * NN;               // 8*32*256 = 65536 f
    float* out_row = g_part + HEADS * GCHUNKS * IN_F;  // 512 f

    k_edst  <<<HEADS * ECHUNKS, 256, 0, stream>>>(hmat, W, a, e_dst);
    k_gpart <<<HEADS * GCHUNKS, 256, 0, stream>>>(hmat, e_dst, g_part);
    k_outrow<<<HEADS,           256, 0, stream>>>(W, g_part, out_row);
    k_bcast <<<2048,            256, 0, stream>>>(out_row, (float4*)out);
}

// Round 3
// 124.863 us; speedup vs baseline: 1.0123x; 1.0123x over previous
//
#include <hip/hip_runtime.h>
#include <hip/hip_bf16.h>

// GAT layer, N=4096, HEADS=8, IN_F=256, OUT_F=64.
// e[h,i,j] = e_src[h,i] + e_dst[h,j]; softmax over j kills e_src -> attention
// row-independent, h_out[h,i,:] == row_h[:] for all i. e_dst = h @ (W[h]@a2[h]),
// row_h = (att^T h) @ W[h]. adj unused. Output reshape is a C-order flatten:
// out[f] = row_{f/(N*O)}[f % O].
//
// 3 kernels: A) e_dst  B) softmax + partial weighted row-sums g_part
//            C) reduce g, row_h = g @ W[h], broadcast-fill 8 MB output.

#define HEADS 8
#define IN_F 256
#define OUT_F 64
#define NN 4096
#define ECHUNKS 16               // A: 256 rows/block
#define GCHUNKS 32               // B: 128 rows/block
#define GROWS (NN / GCHUNKS)     // 128

// ---------------------------------------------------------------------------
// A: e_dst[h,n] = h[n,:] . v[h,:],  v[h,k] = sum_o W[h,k,o]*a2[h,o]
// grid: HEADS*ECHUNKS = 128 blocks x 256 threads
// ---------------------------------------------------------------------------
__global__ void k_edst(const float* __restrict__ hmat,
                       const float* __restrict__ W,
                       const float* __restrict__ a,
                       float* __restrict__ e_dst) {
    const int blk   = blockIdx.x;
    const int head  = blk >> 4;
    const int chunk = blk & (ECHUNKS - 1);
    const int tid   = threadIdx.x;

    __shared__ float a2[OUT_F];
    __shared__ float v[IN_F];

    if (tid < OUT_F) a2[tid] = a[head * 2 * OUT_F + OUT_F + tid];
    __syncthreads();

    {   // v[k], one k per thread
        const float4* Wr = reinterpret_cast<const float4*>(
            W + (size_t)(head * IN_F + tid) * OUT_F);
        float acc = 0.f;
#pragma unroll
        for (int o4 = 0; o4 < OUT_F / 4; ++o4) {
            float4 w4 = Wr[o4];
            acc += w4.x * a2[o4 * 4 + 0] + w4.y * a2[o4 * 4 + 1] +
                   w4.z * a2[o4 * 4 + 2] + w4.w * a2[o4 * 4 + 3];
        }
        v[tid] = acc;
    }
    __syncthreads();

    const int n = chunk * 256 + tid;
    const float4* hr = reinterpret_cast<const float4*>(hmat + (size_t)n * IN_F);
    float acc = 0.f;
#pragma unroll 8
    for (int k4 = 0; k4 < IN_F / 4; ++k4) {
        float4 h4 = hr[k4];
        acc += h4.x * v[k4 * 4 + 0] + h4.y * v[k4 * 4 + 1] +
               h4.z * v[k4 * 4 + 2] + h4.w * v[k4 * 4 + 3];
    }
    e_dst[head * NN + n] = acc;
}

// ---------------------------------------------------------------------------
// B: per (head, 128-row chunk): softmax stats over the full e row (L2-hot),
// then partial g[k] = sum_j att_j * h[j,k].  Wave-shuffle reductions.
// grid: HEADS*GCHUNKS = 256 blocks x 256 threads
// ---------------------------------------------------------------------------
__global__ void k_gpart(const float* __restrict__ hmat,
                        const float* __restrict__ e_dst,
                        float* __restrict__ g_part) {
    const int blk   = blockIdx.x;
    const int head  = blk >> 5;
    const int chunk = blk & (GCHUNKS - 1);
    const int tid   = threadIdx.x;

    __shared__ float wredm[4], wreds[4];
    __shared__ float wts[GROWS];

    const float* e = e_dst + head * NN;

    // max over 4096
    float m = -INFINITY;
    for (int i = tid; i < NN; i += 256) m = fmaxf(m, e[i]);
#pragma unroll
    for (int off = 32; off > 0; off >>= 1) m = fmaxf(m, __shfl_xor(m, off));
    if ((tid & 63) == 0) wredm[tid >> 6] = m;
    __syncthreads();
    m = fmaxf(fmaxf(wredm[0], wredm[1]), fmaxf(wredm[2], wredm[3]));

    // sum of exp
    float ssum = 0.f;
    for (int i = tid; i < NN; i += 256) ssum += __expf(e[i] - m);
#pragma unroll
    for (int off = 32; off > 0; off >>= 1) ssum += __shfl_xor(ssum, off);
    if ((tid & 63) == 0) wreds[tid >> 6] = ssum;
    __syncthreads();
    const float inv = 1.f / (wreds[0] + wreds[1] + wreds[2] + wreds[3]);

    if (tid < GROWS)
        wts[tid] = __expf(e[chunk * GROWS + tid] - m) * inv;
    __syncthreads();

    // partial weighted row-sum; k = tid, coalesced across lanes
    const float* hb = hmat + (size_t)chunk * GROWS * IN_F;
    float acc = 0.f;
#pragma unroll 4
    for (int j = 0; j < GROWS; ++j)
        acc += wts[j] * hb[(size_t)j * IN_F + tid];
    g_part[(size_t)(head * GCHUNKS + chunk) * IN_F + tid] = acc;
}

// ---------------------------------------------------------------------------
// C: per block (512 blocks x 256 threads): head = blk>>6 (block covers 1024
// consecutive float4 of out, all one head). Reduce g_part -> g[256],
// row[o] = sum_k g[k]*W[h,k,o], then write 16 KB of broadcast output.
// ---------------------------------------------------------------------------
__global__ void k_rowout(const float* __restrict__ W,
                         const float* __restrict__ g_part,
                         float4* __restrict__ out) {
    const int blk  = blockIdx.x;
    const int head = blk >> 6;          // 64 blocks per head
    const int tid  = threadIdx.x;

    __shared__ float g[IN_F];
    __shared__ float part[256];
    __shared__ float row[OUT_F];

    float acc = 0.f;
#pragma unroll 8
    for (int c = 0; c < GCHUNKS; ++c)
        acc += g_part[(size_t)(head * GCHUNKS + c) * IN_F + tid];
    g[tid] = acc;
    __syncthreads();

    const int o = tid & 63, grp = tid >> 6;
    float p = 0.f;
#pragma unroll 4
    for (int kk = 0; kk < 64; ++kk) {
        int k = grp * 64 + kk;
        p += g[k] * W[(size_t)(head * IN_F + k) * OUT_F + o];
    }
    part[tid] = p;
    __syncthreads();
    if (tid < OUT_F)
        row[tid] = part[tid] + part[tid + 64] + part[tid + 128] + part[tid + 192];
    __syncthreads();

    const float4* r4 = reinterpret_cast<const float4*>(row);  // 16 float4
    const size_t base = (size_t)blk * 1024;
#pragma unroll
    for (int j = 0; j < 4; ++j) {
        size_t idx = base + (size_t)j * 256 + tid;
        out[idx] = r4[idx & 15];
    }
}

extern "C" void kernel_launch(void* const* d_in, const int* in_sizes, int n_in,
                              void* d_out, int out_size, void* d_ws, size_t ws_size,
                              hipStream_t stream) {
    const float* hmat = (const float*)d_in[0];
    // d_in[1] = adj : UNUSED by the reference
    const float* W = (const float*)d_in[2];
    const float* a = (const float*)d_in[3];
    float* out = (float*)d_out;
    float* ws  = (float*)d_ws;

    float* e_dst  = ws;                  // 8*4096   = 32768 floats
    float* g_part = e_dst + HEADS * NN;  // 8*32*256 = 65536 floats

    k_edst  <<<HEADS * ECHUNKS, 256, 0, stream>>>(hmat, W, a, e_dst);
    k_gpart <<<HEADS * GCHUNKS, 256, 0, stream>>>(hmat, e_dst, g_part);
    k_rowout<<<512,             256, 0, stream>>>(W, g_part, (float4*)out);
}